// Round 9
// baseline (355.444 us; speedup 1.0000x reference)
//
#include <hip/hip_runtime.h>
#include <hip/hip_cooperative_groups.h>

namespace cg = cooperative_groups;

#define NCLASS 19
#define BINS 512
#define NB (NCLASS * BINS)  // 9728 bins
#define NREP 4
#define RPAD 8              // words; shifts each replica's bank phase by 8
#define RSTRIDE (NB + RPAD)
#define FS 16               // fold slices
#define IGNORE_IDX (-100)
#define HW_SHIFT 18  // 512*512 = 2^18 (fixed problem shape)
#define HW_C (1 << HW_SHIFT)

// Load one 2-pixel set: 19 float2 logit streams + int2 labels.
#define LOADSET(V, LB, PIX)                                                  \
  {                                                                          \
    int n_ = (PIX) >> HW_SHIFT;                                              \
    int hw_ = (PIX) & (HW_C - 1);                                            \
    const float* lp_ =                                                       \
        logits + (((size_t)n_ * NCLASS) << HW_SHIFT) + hw_;                  \
    _Pragma("unroll") for (int c_ = 0; c_ < NCLASS; ++c_) {                  \
      float2 q_ = *(const float2*)(lp_ + ((size_t)c_ << HW_SHIFT));          \
      V[c_][0] = q_.x;                                                       \
      V[c_][1] = q_.y;                                                       \
    }                                                                        \
    LB = *(const int2*)(labels + (PIX));                                     \
  }

// Softmax + 2x19 histogram atomics for one 2-pixel set.
#define PROCSET(V, LB)                                                       \
  {                                                                          \
    float m0_ = -3.4e38f, m1_ = -3.4e38f;                                    \
    _Pragma("unroll") for (int c_ = 0; c_ < NCLASS; ++c_) {                  \
      m0_ = fmaxf(m0_, V[c_][0]);                                            \
      m1_ = fmaxf(m1_, V[c_][1]);                                            \
    }                                                                        \
    float s0_ = 0.f, s1_ = 0.f;                                              \
    _Pragma("unroll") for (int c_ = 0; c_ < NCLASS; ++c_) {                  \
      V[c_][0] = __expf(V[c_][0] - m0_); s0_ += V[c_][0];                    \
      V[c_][1] = __expf(V[c_][1] - m1_); s1_ += V[c_][1];                    \
    }                                                                        \
    float i0_ = 1.0f / s0_, i1_ = 1.0f / s1_;                                \
    int l0_ = LB.x, l1_ = LB.y;                                              \
    _Pragma("unroll") for (int c_ = 0; c_ < NCLASS; ++c_) {                  \
      if (l0_ != IGNORE_IDX) {                                               \
        float pr_ = V[c_][0] * i0_;                                          \
        bool pos_ = (c_ == l0_);                                             \
        float e_ = pos_ ? (1.0f - pr_) : pr_;                                \
        int b_ = min(BINS - 1, (int)(e_ * (float)BINS));                     \
        atomicAdd(&sh[rep + (c_ << 9) + b_], pos_ ? 0x10000u : 1u);          \
      }                                                                      \
      if (l1_ != IGNORE_IDX) {                                               \
        float pr_ = V[c_][1] * i1_;                                          \
        bool pos_ = (c_ == l1_);                                             \
        float e_ = pos_ ? (1.0f - pr_) : pr_;                                \
        int b_ = min(BINS - 1, (int)(e_ * (float)BINS));                     \
        atomicAdd(&sh[rep + (c_ << 9) + b_], pos_ ? 0x10000u : 1u);          \
      }                                                                      \
    }                                                                        \
  }

// ---------------------------------------------------------------------------
// Single cooperative kernel. Phase 1 is R7/R8's proven hist core (2 px/thread
// float2 + register double-buffer prefetch + 4-way replicated LDS histogram,
// ~90% of its HBM floor). Then grid.sync() replaces the 3 extra kernel
// launches (~15 us of boundary drain) with ~2 us syncs:
//   P2: 16-slice fold of the R copies (grid-stride, coalesced)
//   P3: 19 blocks: fold slices + 512-wide suffix scan + Lovasz J
//   P4: block 0: fixed-order mean.
// ---------------------------------------------------------------------------
__global__ void __launch_bounds__(1024, 4) lovasz_fused(
    const float* __restrict__ logits, const int* __restrict__ labels,
    unsigned* __restrict__ copies, unsigned long long* __restrict__ part,
    float* __restrict__ partial, float* __restrict__ out, int P, int ppb,
    int R) {
  extern __shared__ unsigned sh[];  // NREP*RSTRIDE words ~= 152 KB
  cg::grid_group grid = cg::this_grid();

  // ---------------- Phase 1: histogram ----------------
  for (int i = threadIdx.x; i < NREP * RSTRIDE; i += 1024) sh[i] = 0u;
  __syncthreads();

  const int rep = (threadIdx.x & 3) * RSTRIDE;
  const int STEP = 1024 * 2;
  int p1 = min(P, blockIdx.x * ppb + ppb);
  int p = blockIdx.x * ppb + (int)threadIdx.x * 2;

  float va[NCLASS][2], vb[NCLASS][2];
  int2 la, lb;
  bool has = p < p1;
  if (has) LOADSET(va, la, p);
  while (has) {
    int pn = p + STEP;
    bool hasn = pn < p1;
    if (hasn) LOADSET(vb, lb, pn);  // prefetch next set
    PROCSET(va, la);
    p = pn;
    has = hasn;
    if (!has) break;
    pn = p + STEP;
    hasn = pn < p1;
    if (hasn) LOADSET(va, la, pn);  // prefetch next set
    PROCSET(vb, lb);
    p = pn;
    has = hasn;
  }
  __syncthreads();

  {
    unsigned* dst = copies + (size_t)blockIdx.x * NB;
    for (int i = threadIdx.x; i < NB; i += 1024)
      dst[i] =
          sh[i] + sh[RSTRIDE + i] + sh[2 * RSTRIDE + i] + sh[3 * RSTRIDE + i];
  }
  __threadfence();
  grid.sync();

  // ---------------- Phase 2: fold copies -> part[FS][NB] ----------------
  for (int gidx = blockIdx.x * 1024 + threadIdx.x; gidx < FS * NB;
       gidx += gridDim.x * 1024) {
    int s = gidx / NB;
    int bin = gidx - s * NB;
    unsigned long long a = 0;
    for (int r = s; r < R; r += FS) {
      unsigned v = copies[(size_t)r * NB + bin];
      a += ((unsigned long long)(v >> 16) << 32) |
           (unsigned long long)(v & 0xffffu);
    }
    part[gidx] = a;
  }
  __threadfence();
  grid.sync();

  // ---------------- Phase 3: per-class suffix scan + Lovasz J ----------
  if (blockIdx.x < NCLASS) {
    int c = blockIdx.x;
    unsigned long long* arr = (unsigned long long*)sh;  // 512 u64 = 4 KB
    int tid = threadIdx.x;

    if (tid < BINS) {
      unsigned long long a = 0;
#pragma unroll
      for (int s = 0; s < FS; ++s) a += part[s * NB + (c << 9) + tid];
      arr[tid] = a;
    }
    __syncthreads();

    // inclusive suffix scan over BINS entries (Hillis-Steele)
    for (int off = 1; off < BINS; off <<= 1) {
      unsigned long long add = 0;
      if (tid < BINS && tid + off < BINS) add = arr[tid + off];
      __syncthreads();
      if (tid < BINS) arr[tid] += add;
      __syncthreads();
    }

    float nPos = (float)(unsigned)(arr[0] >> 32);  // total positives
    float acc = 0.f;
    if (tid >= 1 && tid < BINS) {
      unsigned long long suff = arr[tid];
      float CP = (float)(unsigned)(suff >> 32);
      float CN = (float)(unsigned)(suff & 0xffffffffull);
      float uni = nPos + CN;
      if (uni > 0.f) acc = 1.0f - (nPos - CP) / uni;
    }
    // block reduce over 1024 threads (fixed order)
    for (int off = 32; off > 0; off >>= 1) acc += __shfl_down(acc, off, 64);
    __shared__ float fsum[16];
    int lane = tid & 63, w = tid >> 6;
    if (lane == 0) fsum[w] = acc;
    __syncthreads();
    if (tid == 0) {
      float t = 0.f;
#pragma unroll
      for (int i = 0; i < 16; ++i) t += fsum[i];
      partial[c] = t;
    }
  }
  __threadfence();
  grid.sync();

  // ---------------- Phase 4: fixed-order mean ----------------
  if (blockIdx.x == 0 && threadIdx.x == 0) {
    float t = 0.f;
#pragma unroll
    for (int i = 0; i < NCLASS; ++i) t += partial[i];
    out[0] = t * (1.0f / ((float)BINS * (float)NCLASS));
  }
}

extern "C" void kernel_launch(void* const* d_in, const int* in_sizes, int n_in,
                              void* d_out, int out_size, void* d_ws,
                              size_t ws_size, hipStream_t stream) {
  const float* logits = (const float*)d_in[0];
  const int* labels = (const int*)d_in[1];
  float* out = (float*)d_out;

  int P = in_sizes[1];  // 8*512*512 = 2,097,152

  // Grid = R = copy count; 256 -> 1 block/CU (LDS-limited), co-resident.
  int R = 256;
  while (R > 64 &&
         (size_t)R * NB * 4 + (size_t)FS * NB * 8 + 4096 > ws_size)
    R >>= 1;
  // ppb multiple of 2048 keeps float2/int2 loads aligned. 8192 at R=256;
  // per-replica bin counts <= ppb/4 << 65536 so u16 fields never overflow.
  int ppb = ((P + R - 1) / R + 2047) & ~2047;

  char* ws = (char*)d_ws;
  unsigned* copies = (unsigned*)ws;
  unsigned long long* part = (unsigned long long*)(ws + (size_t)R * NB * 4);
  float* partial = (float*)(part + (size_t)FS * NB);

  size_t ldsBytes = (size_t)NREP * RSTRIDE * 4;  // ~152 KB -> 1 block/CU

  void* args[] = {(void*)&logits, (void*)&labels, (void*)&copies,
                  (void*)&part,   (void*)&partial, (void*)&out,
                  (void*)&P,      (void*)&ppb,     (void*)&R};
  hipLaunchCooperativeKernel((const void*)lovasz_fused, dim3(R), dim3(1024),
                             args, (unsigned)ldsBytes, stream);
}

// Round 10
// 76.453 us; speedup vs baseline: 4.6492x; 4.6492x over previous
//
#include <hip/hip_runtime.h>
#include <hip/hip_bf16.h>

#define NCLASS 19
#define BINS 512
#define NB (NCLASS * BINS)  // 9728 bins
#define NREP 4
#define RPAD 8              // words; shifts each replica's bank phase by 8
#define RSTRIDE (NB + RPAD)
#define SLICES 8
#define NGRID (SLICES * (NB / 256))  // 304 tail blocks
#define IGNORE_IDX (-100)
#define HW_SHIFT 18  // 512*512 = 2^18 (fixed problem shape)
#define HW_C (1 << HW_SHIFT)

#define UNPACK(v)                                            \
  (((unsigned long long)((v) >> 16) << 32) |                 \
   (unsigned long long)((v) & 0xffffu))

// Load one 2-pixel set: 19 float2 logit streams + int2 labels.
#define LOADSET(V, LB, PIX)                                                  \
  {                                                                          \
    int n_ = (PIX) >> HW_SHIFT;                                              \
    int hw_ = (PIX) & (HW_C - 1);                                            \
    const float* lp_ =                                                       \
        logits + (((size_t)n_ * NCLASS) << HW_SHIFT) + hw_;                  \
    _Pragma("unroll") for (int c_ = 0; c_ < NCLASS; ++c_) {                  \
      float2 q_ = *(const float2*)(lp_ + ((size_t)c_ << HW_SHIFT));          \
      V[c_][0] = q_.x;                                                       \
      V[c_][1] = q_.y;                                                       \
    }                                                                        \
    LB = *(const int2*)(labels + (PIX));                                     \
  }

// Softmax + 2x19 histogram atomics for one 2-pixel set.
#define PROCSET(V, LB)                                                       \
  {                                                                          \
    float m0_ = -3.4e38f, m1_ = -3.4e38f;                                    \
    _Pragma("unroll") for (int c_ = 0; c_ < NCLASS; ++c_) {                  \
      m0_ = fmaxf(m0_, V[c_][0]);                                            \
      m1_ = fmaxf(m1_, V[c_][1]);                                            \
    }                                                                        \
    float s0_ = 0.f, s1_ = 0.f;                                              \
    _Pragma("unroll") for (int c_ = 0; c_ < NCLASS; ++c_) {                  \
      V[c_][0] = __expf(V[c_][0] - m0_); s0_ += V[c_][0];                    \
      V[c_][1] = __expf(V[c_][1] - m1_); s1_ += V[c_][1];                    \
    }                                                                        \
    float i0_ = 1.0f / s0_, i1_ = 1.0f / s1_;                                \
    int l0_ = LB.x, l1_ = LB.y;                                              \
    _Pragma("unroll") for (int c_ = 0; c_ < NCLASS; ++c_) {                  \
      if (l0_ != IGNORE_IDX) {                                               \
        float pr_ = V[c_][0] * i0_;                                          \
        bool pos_ = (c_ == l0_);                                             \
        float e_ = pos_ ? (1.0f - pr_) : pr_;                                \
        int b_ = min(BINS - 1, (int)(e_ * (float)BINS));                     \
        atomicAdd(&sh[rep + (c_ << 9) + b_], pos_ ? 0x10000u : 1u);          \
      }                                                                      \
      if (l1_ != IGNORE_IDX) {                                               \
        float pr_ = V[c_][1] * i1_;                                          \
        bool pos_ = (c_ == l1_);                                             \
        float e_ = pos_ ? (1.0f - pr_) : pr_;                                \
        int b_ = min(BINS - 1, (int)(e_ * (float)BINS));                     \
        atomicAdd(&sh[rep + (c_ << 9) + b_], pos_ ? 0x10000u : 1u);          \
      }                                                                      \
    }                                                                        \
  }

// ---------------------------------------------------------------------------
// Phase 1 (proven R7/R8 core, VERBATIM — ~29 us ~= HBM floor): 2 px/thread
// float2 loads, 4-way lane-replicated LDS histogram (u32-packed pos<<16|neg),
// register double-buffer prefetch with named A/B sets (rule #20).
// ---------------------------------------------------------------------------
__global__ void __launch_bounds__(1024, 4) hist_pf(
    const float* __restrict__ logits, const int* __restrict__ labels,
    unsigned* __restrict__ copies, int P, int ppb) {
  extern __shared__ unsigned sh[];  // NREP*RSTRIDE words ~= 152 KB
  for (int i = threadIdx.x; i < NREP * RSTRIDE; i += 1024) sh[i] = 0u;
  __syncthreads();

  const int rep = (threadIdx.x & 3) * RSTRIDE;
  const int STEP = 1024 * 2;
  int p1 = min(P, blockIdx.x * ppb + ppb);
  int p = blockIdx.x * ppb + (int)threadIdx.x * 2;

  float va[NCLASS][2], vb[NCLASS][2];
  int2 la, lb;
  bool has = p < p1;
  if (has) LOADSET(va, la, p);
  while (has) {
    int pn = p + STEP;
    bool hasn = pn < p1;
    if (hasn) LOADSET(vb, lb, pn);  // prefetch next set
    PROCSET(va, la);
    p = pn;
    has = hasn;
    if (!has) break;
    pn = p + STEP;
    hasn = pn < p1;
    if (hasn) LOADSET(va, la, pn);  // prefetch next set
    PROCSET(vb, lb);
    p = pn;
    has = hasn;
  }
  __syncthreads();

  unsigned* dst = copies + (size_t)blockIdx.x * NB;
  for (int i = threadIdx.x; i < NB; i += 1024)
    dst[i] =
        sh[i] + sh[RSTRIDE + i] + sh[2 * RSTRIDE + i] + sh[3 * RSTRIDE + i];
}

// ---------------------------------------------------------------------------
// Fused tail (threadfence-reduction pattern; ordinary launch, deterministic):
//  Stage A (all 304 blocks): 8-slice coalesced fold of the R copies into
//    part[SLICES][NB], 4 independent accumulators for ILP.
//  Ticket: last NCLASS tickets spin until all 304 done (they already finished
//    stage A -> no deadlock), then each folds+scans ONE class (proven
//    scan19_fold body) and writes partial[c].
//  Second ticket: 19th incrementer sums partial[0..18] in fixed order -> out.
// ---------------------------------------------------------------------------
__global__ void __launch_bounds__(256) tail_fused(
    const unsigned* __restrict__ copies, unsigned long long* __restrict__ part,
    float* __restrict__ partial, unsigned* __restrict__ counters,
    float* __restrict__ out, int R) {
  const int nblk = NB / 256;  // 38
  int s = blockIdx.x / nblk;
  int blk = blockIdx.x - s * nblk;
  int cb = blk * 256 + threadIdx.x;
  int tid = threadIdx.x;

  // ---- Stage A: fold copies -> part[s][cb] (R/SLICES is a multiple of 4) --
  unsigned long long a0 = 0, a1 = 0, a2 = 0, a3 = 0;
  for (int r = s; r < R; r += 4 * SLICES) {
    unsigned v0 = copies[(size_t)r * NB + cb];
    unsigned v1 = copies[(size_t)(r + SLICES) * NB + cb];
    unsigned v2 = copies[(size_t)(r + 2 * SLICES) * NB + cb];
    unsigned v3 = copies[(size_t)(r + 3 * SLICES) * NB + cb];
    a0 += UNPACK(v0);
    a1 += UNPACK(v1);
    a2 += UNPACK(v2);
    a3 += UNPACK(v3);
  }
  part[(size_t)s * NB + cb] = (a0 + a1) + (a2 + a3);

  // ---- Ticket ----
  __shared__ unsigned tk;
  __threadfence();
  __syncthreads();
  if (tid == 0) tk = atomicAdd(&counters[0], 1u);
  __syncthreads();
  unsigned ticket = tk;
  if (ticket < NGRID - NCLASS) return;
  int c = (int)ticket - (NGRID - NCLASS);

  // ---- Spin until all stage-A results visible ----
  if (tid == 0) {
    while (__hip_atomic_load(&counters[0], __ATOMIC_ACQUIRE,
                             __HIP_MEMORY_SCOPE_AGENT) < NGRID) {
    }
  }
  __syncthreads();
  __threadfence();

  // ---- Per-class fold + suffix scan + Lovasz J (proven scan19_fold body) --
  __shared__ unsigned long long bins[BINS];
  __shared__ unsigned long long arr[256];
  __shared__ unsigned long long wsum[4];
  __shared__ float fsum[4];

  for (int i = tid; i < BINS; i += 256) {
    unsigned long long a = 0;
#pragma unroll
    for (int sl = 0; sl < SLICES; ++sl)
      a += part[(size_t)sl * NB + (c << 9) + i];
    bins[i] = a;
  }
  __syncthreads();

  unsigned long long t = 0;
  for (int i = tid; i < BINS; i += 256) t += bins[i];
  for (int off = 32; off > 0; off >>= 1) t += __shfl_down(t, off, 64);
  int lane = tid & 63, w = tid >> 6;
  if (lane == 0) wsum[w] = t;
  __syncthreads();
  unsigned long long total = wsum[0] + wsum[1] + wsum[2] + wsum[3];
  float nPos = (float)(unsigned)(total >> 32);

  unsigned long long above = 0;
  float acc = 0.f;
  for (int r = BINS / 256 - 1; r >= 0; --r) {
    arr[tid] = bins[r * 256 + tid];
    __syncthreads();
    for (int off = 1; off < 256; off <<= 1) {
      unsigned long long add = (tid + off < 256) ? arr[tid + off] : 0ull;
      __syncthreads();
      arr[tid] += add;
      __syncthreads();
    }
    unsigned long long suff = arr[tid] + above;
    unsigned long long rowTot = arr[0];
    __syncthreads();

    int gb = r * 256 + tid;
    if (gb >= 1) {
      float CP = (float)(unsigned)(suff >> 32);
      float CN = (float)(unsigned)(suff & 0xffffffffull);
      float uni = nPos + CN;
      if (uni > 0.f) acc += 1.0f - (nPos - CP) / uni;
    }
    above += rowTot;
  }

  for (int off = 32; off > 0; off >>= 1) acc += __shfl_down(acc, off, 64);
  if (lane == 0) fsum[w] = acc;
  __syncthreads();

  // ---- Final fixed-order mean by the 19th finisher ----
  if (tid == 0) {
    partial[c] = fsum[0] + fsum[1] + fsum[2] + fsum[3];
    __threadfence();
    unsigned t2 = atomicAdd(&counters[1], 1u);
    if (t2 == NCLASS - 1) {
      __threadfence();
      float m = 0.f;
#pragma unroll
      for (int i = 0; i < NCLASS; ++i) m += partial[i];
      out[0] = m * (1.0f / ((float)BINS * (float)NCLASS));
    }
  }
}

extern "C" void kernel_launch(void* const* d_in, const int* in_sizes, int n_in,
                              void* d_out, int out_size, void* d_ws,
                              size_t ws_size, hipStream_t stream) {
  const float* logits = (const float*)d_in[0];
  const int* labels = (const int*)d_in[1];
  float* out = (float*)d_out;

  const int P = in_sizes[1];  // 8*512*512 = 2,097,152

  // R = copy count = hist grid; 256 = 1 block/CU. Shrink if ws is tiny
  // (R/SLICES stays a multiple of 4 down to R=32).
  int R = 256;
  while (R > 32 &&
         (size_t)R * NB * 4 + (size_t)SLICES * NB * 8 + 4096 > ws_size)
    R >>= 1;
  // ppb multiple of 2048 keeps float2/int2 loads aligned. 8192 at R=256.
  int ppb = ((P + R - 1) / R + 2047) & ~2047;

  char* ws = (char*)d_ws;
  unsigned* copies = (unsigned*)ws;
  unsigned long long* part = (unsigned long long*)(ws + (size_t)R * NB * 4);
  float* partial = (float*)(part + (size_t)SLICES * NB);
  unsigned* counters = (unsigned*)(partial + 32);  // aligned, past partial

  size_t ldsBytes = (size_t)NREP * RSTRIDE * 4;  // ~152 KB -> 1 block/CU

  // Counters must be zero at the start of EVERY call (graph replays do not
  // re-poison): tiny async memset is capture-safe.
  hipMemsetAsync(counters, 0, 2 * sizeof(unsigned), stream);

  hist_pf<<<R, 1024, ldsBytes, stream>>>(logits, labels, copies, P, ppb);
  tail_fused<<<NGRID, 256, 0, stream>>>(copies, part, partial, counters, out,
                                        R);
}

// Round 11
// 49.441 us; speedup vs baseline: 7.1893x; 1.5463x over previous
//
#include <hip/hip_runtime.h>
#include <hip/hip_bf16.h>

#define NCLASS 19
#define BINS 512
#define NB (NCLASS * BINS)  // 9728 bins
#define NREP 4
#define RPAD 8              // words; shifts each replica's bank phase by 8
#define RSTRIDE (NB + RPAD)
#define IGNORE_IDX (-100)
#define HW_SHIFT 18  // 512*512 = 2^18 (fixed problem shape)
#define HW_C (1 << HW_SHIFT)

#define UNPACK(v)                                            \
  (((unsigned long long)((v) >> 16) << 32) |                 \
   (unsigned long long)((v) & 0xffffu))

// Load one 2-pixel set: 19 float2 logit streams + int2 labels.
#define LOADSET(V, LB, PIX)                                                  \
  {                                                                          \
    int n_ = (PIX) >> HW_SHIFT;                                              \
    int hw_ = (PIX) & (HW_C - 1);                                            \
    const float* lp_ =                                                       \
        logits + (((size_t)n_ * NCLASS) << HW_SHIFT) + hw_;                  \
    _Pragma("unroll") for (int c_ = 0; c_ < NCLASS; ++c_) {                  \
      float2 q_ = *(const float2*)(lp_ + ((size_t)c_ << HW_SHIFT));          \
      V[c_][0] = q_.x;                                                       \
      V[c_][1] = q_.y;                                                       \
    }                                                                        \
    LB = *(const int2*)(labels + (PIX));                                     \
  }

// Softmax + 2x19 histogram atomics for one 2-pixel set.
#define PROCSET(V, LB)                                                       \
  {                                                                          \
    float m0_ = -3.4e38f, m1_ = -3.4e38f;                                    \
    _Pragma("unroll") for (int c_ = 0; c_ < NCLASS; ++c_) {                  \
      m0_ = fmaxf(m0_, V[c_][0]);                                            \
      m1_ = fmaxf(m1_, V[c_][1]);                                            \
    }                                                                        \
    float s0_ = 0.f, s1_ = 0.f;                                              \
    _Pragma("unroll") for (int c_ = 0; c_ < NCLASS; ++c_) {                  \
      V[c_][0] = __expf(V[c_][0] - m0_); s0_ += V[c_][0];                    \
      V[c_][1] = __expf(V[c_][1] - m1_); s1_ += V[c_][1];                    \
    }                                                                        \
    float i0_ = 1.0f / s0_, i1_ = 1.0f / s1_;                                \
    int l0_ = LB.x, l1_ = LB.y;                                              \
    _Pragma("unroll") for (int c_ = 0; c_ < NCLASS; ++c_) {                  \
      if (l0_ != IGNORE_IDX) {                                               \
        float pr_ = V[c_][0] * i0_;                                          \
        bool pos_ = (c_ == l0_);                                             \
        float e_ = pos_ ? (1.0f - pr_) : pr_;                                \
        int b_ = min(BINS - 1, (int)(e_ * (float)BINS));                     \
        atomicAdd(&sh[rep + (c_ << 9) + b_], pos_ ? 0x10000u : 1u);          \
      }                                                                      \
      if (l1_ != IGNORE_IDX) {                                               \
        float pr_ = V[c_][1] * i1_;                                          \
        bool pos_ = (c_ == l1_);                                             \
        float e_ = pos_ ? (1.0f - pr_) : pr_;                                \
        int b_ = min(BINS - 1, (int)(e_ * (float)BINS));                     \
        atomicAdd(&sh[rep + (c_ << 9) + b_], pos_ ? 0x10000u : 1u);          \
      }                                                                      \
    }                                                                        \
  }

// ---------------------------------------------------------------------------
// Phase 1 (proven R7/R8 core, VERBATIM — ~31 us ~= 92% of its HBM floor):
// 2 px/thread float2 loads, 4-way lane-replicated LDS histogram (u32-packed
// pos<<16|neg), register double-buffer prefetch with named A/B sets.
// ---------------------------------------------------------------------------
__global__ void __launch_bounds__(1024, 4) hist_pf(
    const float* __restrict__ logits, const int* __restrict__ labels,
    unsigned* __restrict__ copies, int P, int ppb) {
  extern __shared__ unsigned sh[];  // NREP*RSTRIDE words ~= 152 KB
  for (int i = threadIdx.x; i < NREP * RSTRIDE; i += 1024) sh[i] = 0u;
  __syncthreads();

  const int rep = (threadIdx.x & 3) * RSTRIDE;
  const int STEP = 1024 * 2;
  int p1 = min(P, blockIdx.x * ppb + ppb);
  int p = blockIdx.x * ppb + (int)threadIdx.x * 2;

  float va[NCLASS][2], vb[NCLASS][2];
  int2 la, lb;
  bool has = p < p1;
  if (has) LOADSET(va, la, p);
  while (has) {
    int pn = p + STEP;
    bool hasn = pn < p1;
    if (hasn) LOADSET(vb, lb, pn);  // prefetch next set
    PROCSET(va, la);
    p = pn;
    has = hasn;
    if (!has) break;
    pn = p + STEP;
    hasn = pn < p1;
    if (hasn) LOADSET(va, la, pn);  // prefetch next set
    PROCSET(vb, lb);
    p = pn;
    has = hasn;
  }
  __syncthreads();

  unsigned* dst = copies + (size_t)blockIdx.x * NB;
  for (int i = threadIdx.x; i < NB; i += 1024)
    dst[i] =
        sh[i] + sh[RSTRIDE + i] + sh[2 * RSTRIDE + i] + sh[3 * RSTRIDE + i];
}

// ---------------------------------------------------------------------------
// Phase 2: direct fold + scan, one block per class, 1024 threads.
// Latency engineering (the R7 scan_direct lesson): 2 threads per bin, each
// folding R/2 copies with 8 INDEPENDENT accumulators -> only R/16 dependent
// rounds of coalesced 256B/wave loads; halves combined via LDS. Then one
// 512-wide Hillis-Steele inclusive suffix scan (9 rounds) and the Lovasz J
// accumulation: loss_c = (1/BINS) * sum_{b>=1} J_b with (CP,CN) the
// inclusive suffix counts at bin b. nPos = suffix at bin 0 = class total.
// ---------------------------------------------------------------------------
__global__ void __launch_bounds__(1024) scan19_direct(
    const unsigned* __restrict__ copies, float* __restrict__ partial, int R) {
  int c = blockIdx.x;
  __shared__ unsigned long long binsA[BINS];  // 4 KB (also scan array)
  __shared__ unsigned long long binsB[BINS];  // 4 KB
  __shared__ float fsum[16];
  int tid = threadIdx.x;
  int bin = tid & (BINS - 1);
  int half = tid >> 9;  // 0 or 1

  // ---- fold: each thread sums R/2 copies for its bin, 8-way ILP ----
  int hc = R >> 1;            // copies per half (128 at R=256)
  int r0 = half * hc;
  const unsigned* base = copies + (c << 9) + bin;
  unsigned long long a0 = 0, a1 = 0, a2 = 0, a3 = 0, a4 = 0, a5 = 0, a6 = 0,
                     a7 = 0;
  for (int r = 0; r < hc; r += 8) {
    unsigned v0 = base[(size_t)(r0 + r + 0) * NB];
    unsigned v1 = base[(size_t)(r0 + r + 1) * NB];
    unsigned v2 = base[(size_t)(r0 + r + 2) * NB];
    unsigned v3 = base[(size_t)(r0 + r + 3) * NB];
    unsigned v4 = base[(size_t)(r0 + r + 4) * NB];
    unsigned v5 = base[(size_t)(r0 + r + 5) * NB];
    unsigned v6 = base[(size_t)(r0 + r + 6) * NB];
    unsigned v7 = base[(size_t)(r0 + r + 7) * NB];
    a0 += UNPACK(v0);
    a1 += UNPACK(v1);
    a2 += UNPACK(v2);
    a3 += UNPACK(v3);
    a4 += UNPACK(v4);
    a5 += UNPACK(v5);
    a6 += UNPACK(v6);
    a7 += UNPACK(v7);
  }
  unsigned long long a = ((a0 + a1) + (a2 + a3)) + ((a4 + a5) + (a6 + a7));
  if (half == 0)
    binsA[bin] = a;
  else
    binsB[bin] = a;
  __syncthreads();
  if (half == 0) binsA[bin] += binsB[bin];
  __syncthreads();

  // ---- inclusive suffix scan over BINS entries (Hillis-Steele, 9 rounds) --
  for (int off = 1; off < BINS; off <<= 1) {
    unsigned long long add = 0;
    if (half == 0 && bin + off < BINS) add = binsA[bin + off];
    __syncthreads();
    if (half == 0) binsA[bin] += add;
    __syncthreads();
  }

  float nPos = (float)(unsigned)(binsA[0] >> 32);  // class total positives
  float acc = 0.f;
  if (half == 0 && bin >= 1) {
    unsigned long long suff = binsA[bin];
    float CP = (float)(unsigned)(suff >> 32);
    float CN = (float)(unsigned)(suff & 0xffffffffull);
    float uni = nPos + CN;
    if (uni > 0.f) acc = 1.0f - (nPos - CP) / uni;
  }

  // ---- block reduce (fixed order) ----
  for (int off = 32; off > 0; off >>= 1) acc += __shfl_down(acc, off, 64);
  int lane = tid & 63, w = tid >> 6;
  if (lane == 0) fsum[w] = acc;
  __syncthreads();
  if (tid == 0) {
    float t = 0.f;
#pragma unroll
    for (int i = 0; i < 16; ++i) t += fsum[i];
    partial[c] = t;
  }
}

// ---------------------------------------------------------------------------
// Phase 3: mean over classes (fixed-order, deterministic).
// ---------------------------------------------------------------------------
__global__ void __launch_bounds__(64) lovasz_final(
    const float* __restrict__ partial, float* __restrict__ out, int n,
    float scale) {
  float acc = 0.f;
  for (int i = threadIdx.x; i < n; i += 64) acc += partial[i];
  for (int off = 32; off > 0; off >>= 1) acc += __shfl_down(acc, off, 64);
  if (threadIdx.x == 0) out[0] = acc * scale;
}

extern "C" void kernel_launch(void* const* d_in, const int* in_sizes, int n_in,
                              void* d_out, int out_size, void* d_ws,
                              size_t ws_size, hipStream_t stream) {
  const float* logits = (const float*)d_in[0];
  const int* labels = (const int*)d_in[1];
  float* out = (float*)d_out;

  const int P = in_sizes[1];  // 8*512*512 = 2,097,152

  // R = copy count = hist grid; 256 = 1 block/CU. Shrink if ws is tiny
  // (R/2 stays a multiple of 8 down to R=16).
  int R = 256;
  while (R > 32 && (size_t)R * NB * 4 + 4096 > ws_size) R >>= 1;
  // ppb multiple of 2048 keeps float2/int2 loads aligned. 8192 at R=256.
  int ppb = ((P + R - 1) / R + 2047) & ~2047;

  char* ws = (char*)d_ws;
  unsigned* copies = (unsigned*)ws;
  float* partial = (float*)(ws + (size_t)R * NB * 4);

  size_t ldsBytes = (size_t)NREP * RSTRIDE * 4;  // ~152 KB -> 1 block/CU

  hist_pf<<<R, 1024, ldsBytes, stream>>>(logits, labels, copies, P, ppb);
  scan19_direct<<<NCLASS, 1024, 0, stream>>>(copies, partial, R);
  lovasz_final<<<1, 64, 0, stream>>>(partial, out, NCLASS,
                                     1.0f / ((float)BINS * (float)NCLASS));
}